// Round 3
// baseline (121.572 us; speedup 1.0000x reference)
//
#include <hip/hip_runtime.h>

// loss = sum_i w[i] * sqrt( (0.5*kx+0.5 - rx)^2 + (0.5 - 0.5*ky - ry)^2 )
// z channel / z_norm in the reference is dead code (never feeds loss).
// Inputs (96 MiB) are L3-resident across bench iterations (round-1 rocprof:
// FETCH_SIZE ~50 MB << 100.7 MB mandatory) -> the limiter is the L1/TA path,
// not HBM.
//
// Round-3 change: the direct AoS float4 loads are per-instruction uncoalesced
// (48 B lane stride on kp3d -> each load touches 3x the cachelines it uses;
// 32 B stride on ref -> 2x). Fix: stage each block's 48 KB slice into LDS
// with fully-coalesced loads (consecutive lanes -> consecutive 16 B), then
// run the BIT-IDENTICAL compute phase reading from LDS. Each thread consumes
// exactly the same bytes as before -> same math tree, same reduction order,
// absmax 0.0 preserved. LDS reads at 48 B stride hit bank-group 3t mod 8
// (a permutation per 8-lane octet) -> conflict-free.
//
// Round-1 lesson kept: never per-block agent-scope fence/atomic on gfx950
// (~95 ns/block serialized L2 writeback -> 195 us). Two-kernel structure.

#define TPB 256

__global__ __launch_bounds__(TPB) void viewpoint_partial_kernel(
    const float* __restrict__ kp3d,   // B*N*3 floats, AoS (x,y,z)
    const float* __restrict__ ref,    // B*N*2 floats, AoS (rx,ry)
    const float* __restrict__ w,      // B*N floats
    float* __restrict__ partials,     // one float per block (d_ws)
    int T)                            // total threads; each handles groups tid, tid+T
{
    const float4* kp4 = (const float4*)kp3d;
    const float4* rf4 = (const float4*)ref;
    const float4* w4  = (const float4*)w;

    // LDS layout in float4 granules:
    //   kp_g0  [0,768)    kp_g1  [768,1536)
    //   ref_g0 [1536,2048) ref_g1 [2048,2560)
    //   w_g0   [2560,2816) w_g1   [2816,3072)
    __shared__ float4 lds[3072];   // 48 KB -> 3 blocks/CU

    const int t = threadIdx.x;

    // ---- Coalesced staging: 12 float4 loads/thread, lane-consecutive ----
    const int kpb0 = 768 * blockIdx.x;          // kp granule base, group-0 slice
    const int kpb1 = kpb0 + 3 * T;              // group-1 slice
    const int rfb0 = 512 * blockIdx.x;
    const int rfb1 = rfb0 + 2 * T;
    const int wb0  = 256 * blockIdx.x;
    const int wb1  = wb0 + T;

    float4 s0  = kp4[kpb0 + t];
    float4 s1  = kp4[kpb0 + t + 256];
    float4 s2  = kp4[kpb0 + t + 512];
    float4 s3  = kp4[kpb1 + t];
    float4 s4  = kp4[kpb1 + t + 256];
    float4 s5  = kp4[kpb1 + t + 512];
    float4 s6  = rf4[rfb0 + t];
    float4 s7  = rf4[rfb0 + t + 256];
    float4 s8  = rf4[rfb1 + t];
    float4 s9  = rf4[rfb1 + t + 256];
    float4 s10 = w4[wb0 + t];
    float4 s11 = w4[wb1 + t];

    // Pin all 12 loads before any LDS write (single waitcnt, max MLP).
    asm volatile("" ::
        "v"(s0.x), "v"(s1.x), "v"(s2.x), "v"(s3.x), "v"(s4.x), "v"(s5.x),
        "v"(s6.x), "v"(s7.x), "v"(s8.x), "v"(s9.x), "v"(s10.x), "v"(s11.x));

    lds[0    + t]       = s0;
    lds[0    + t + 256] = s1;
    lds[0    + t + 512] = s2;
    lds[768  + t]       = s3;
    lds[768  + t + 256] = s4;
    lds[768  + t + 512] = s5;
    lds[1536 + t]       = s6;
    lds[1536 + t + 256] = s7;
    lds[2048 + t]       = s8;
    lds[2048 + t + 256] = s9;
    lds[2560 + t]       = s10;
    lds[2816 + t]       = s11;

    __syncthreads();

    // ---- Compute phase: identical bytes, identical math tree as before ----
    float4 a0 = lds[3 * t + 0];        // x0 y0 z0 x1
    float4 a1 = lds[3 * t + 1];        // y1 z1 x2 y2
    float4 a2 = lds[3 * t + 2];        // z2 x3 y3 z3
    float4 b0 = lds[768 + 3 * t + 0];
    float4 b1 = lds[768 + 3 * t + 1];
    float4 b2 = lds[768 + 3 * t + 2];
    float4 r00 = lds[1536 + 2 * t + 0];  // rx0 ry0 rx1 ry1
    float4 r01 = lds[1536 + 2 * t + 1];  // rx2 ry2 rx3 ry3
    float4 r10 = lds[2048 + 2 * t + 0];
    float4 r11 = lds[2048 + 2 * t + 1];
    float4 w0 = lds[2560 + t];
    float4 w1 = lds[2816 + t];

    float acc = 0.0f;
    float dx, dy;

    // group 0: points 4*g0 .. 4*g0+3
    dx = fmaf(a0.x, 0.5f, 0.5f) - r00.x;
    dy = fmaf(a0.y, -0.5f, 0.5f) - r00.y;
    acc += w0.x * sqrtf(fmaf(dx, dx, dy * dy));

    dx = fmaf(a0.w, 0.5f, 0.5f) - r00.z;
    dy = fmaf(a1.x, -0.5f, 0.5f) - r00.w;
    acc += w0.y * sqrtf(fmaf(dx, dx, dy * dy));

    dx = fmaf(a1.z, 0.5f, 0.5f) - r01.x;
    dy = fmaf(a1.w, -0.5f, 0.5f) - r01.y;
    acc += w0.z * sqrtf(fmaf(dx, dx, dy * dy));

    dx = fmaf(a2.y, 0.5f, 0.5f) - r01.z;
    dy = fmaf(a2.z, -0.5f, 0.5f) - r01.w;
    acc += w0.w * sqrtf(fmaf(dx, dx, dy * dy));

    // group 1
    dx = fmaf(b0.x, 0.5f, 0.5f) - r10.x;
    dy = fmaf(b0.y, -0.5f, 0.5f) - r10.y;
    acc += w1.x * sqrtf(fmaf(dx, dx, dy * dy));

    dx = fmaf(b0.w, 0.5f, 0.5f) - r10.z;
    dy = fmaf(b1.x, -0.5f, 0.5f) - r10.w;
    acc += w1.y * sqrtf(fmaf(dx, dx, dy * dy));

    dx = fmaf(b1.z, 0.5f, 0.5f) - r11.x;
    dy = fmaf(b1.w, -0.5f, 0.5f) - r11.y;
    acc += w1.z * sqrtf(fmaf(dx, dx, dy * dy));

    dx = fmaf(b2.y, 0.5f, 0.5f) - r11.z;
    dy = fmaf(b2.z, -0.5f, 0.5f) - r11.w;
    acc += w1.w * sqrtf(fmaf(dx, dx, dy * dy));

    // wave-64 butterfly reduction
    #pragma unroll
    for (int off = 32; off > 0; off >>= 1)
        acc += __shfl_down(acc, off, 64);

    __shared__ float wave_sums[TPB / 64];
    int lane = threadIdx.x & 63;
    int wid  = threadIdx.x >> 6;
    if (lane == 0) wave_sums[wid] = acc;
    __syncthreads();

    if (threadIdx.x == 0) {
        partials[blockIdx.x] = wave_sums[0] + wave_sums[1]
                             + wave_sums[2] + wave_sums[3];
    }
}

__global__ __launch_bounds__(256) void final_reduce_kernel(
    const float* __restrict__ partials, float* __restrict__ out, int n)
{
    float acc = 0.0f;
    for (int i = threadIdx.x; i < n; i += 256)
        acc += partials[i];

    #pragma unroll
    for (int off = 32; off > 0; off >>= 1)
        acc += __shfl_down(acc, off, 64);

    __shared__ float wave_sums[4];
    int lane = threadIdx.x & 63;
    int wid  = threadIdx.x >> 6;
    if (lane == 0) wave_sums[wid] = acc;
    __syncthreads();

    if (threadIdx.x == 0)
        out[0] = wave_sums[0] + wave_sums[1] + wave_sums[2] + wave_sums[3];
}

extern "C" void kernel_launch(void* const* d_in, const int* in_sizes, int n_in,
                              void* d_out, int out_size, void* d_ws, size_t ws_size,
                              hipStream_t stream) {
    const float* kp3d = (const float*)d_in[0];
    const float* ref  = (const float*)d_in[1];
    const float* w    = (const float*)d_in[2];
    float* out = (float*)d_out;
    float* partials = (float*)d_ws;

    int npts = in_sizes[2];        // B*N = 4194304
    int ngroups = npts / 4;        // 1048576 (exactly divisible)
    int T = ngroups / 2;           // 524288 threads, 2 groups each
    int blocks = T / TPB;          // 2048

    viewpoint_partial_kernel<<<blocks, TPB, 0, stream>>>(kp3d, ref, w, partials, T);
    final_reduce_kernel<<<1, 256, 0, stream>>>(partials, out, blocks);
}